// Round 7
// baseline (131.894 us; speedup 1.0000x reference)
//
#include <hip/hip_runtime.h>
#include <stdint.h>

// Problem constants (fixed by the reference)
#define NB    32768   // batch
#define NS    16      // states per element
#define SS    32      // state size (K of stage 1)
#define ENCD  64      // encoder width
#define HIDD  128     // hidden width
#define OUTD  8       // output logits
#define BT    32      // batch elements per block
#define THREADS 512   // 8 waves

typedef _Float16 half8 __attribute__((ext_vector_type(8)));  // 8 f16 = 4 VGPRs
typedef float    f32x4 __attribute__((ext_vector_type(4)));

#define MFMA(a, b, c) __builtin_amdgcn_mfma_f32_16x16x32_f16((a), (b), (c), 0, 0, 0)

__device__ __forceinline__ half8 pack8(const float* f) {
  half8 h;
#pragma unroll
  for (int j = 0; j < 8; ++j) h[j] = (_Float16)f[j];
  return h;
}

// R7: 8192 waves (R5's winning count, 32/CU) + halved per-wave weight VMEM.
// Wave w of each 8-wave block: stage-1 for 4 batch elems; stage-3 N-tile w
// reused across both M-tiles (W_f gather once per wave); stage-4 waves 0-1.
// R6 lesson: latency-bound — maximize waves, minimize per-wave serial chain.
__global__ __launch_bounds__(THREADS, 8)   // 8 waves/EU -> 4 blocks/CU, VGPR<=64
void gnn_fused(const float* __restrict__ obs,
               const float* __restrict__ W_enc,
               const float* __restrict__ b_enc,
               const float* __restrict__ W_f,
               const float* __restrict__ b_f,
               const float* __restrict__ W_dec,
               const float* __restrict__ b_dec,
               float* __restrict__ out)
{
  // fp16 LDS, row stride 136 halfs = 272 B (16B-aligned rows, bank-skewed)
  __shared__ __align__(16) _Float16 f_in[BT][136];  // stage-2 out [batch][128]
  __shared__ __align__(16) _Float16 hidn[BT][136];  // stage-3 out [batch][128]

  const int tid  = threadIdx.x;
  const int w    = tid >> 6;     // wave 0..7
  const int l    = tid & 63;     // lane
  const int m15  = l & 15;
  const int quad = l >> 4;
  const int b0   = blockIdx.x * BT;

  // ---- stage-1 A-data: 4 elems, loads all in flight, packed to fp16 at once
  const float* bp = obs + (size_t)(b0 + w * 4) * (NS * SS) + m15 * SS + quad * 8;
  half8 a4[4];
#pragma unroll
  for (int d = 0; d < 4; ++d) {
    const float* p = bp + (size_t)d * (NS * SS);
    float4 c0 = ((const float4*)p)[0];
    float4 c1 = ((const float4*)p)[1];
    float f[8] = {c0.x, c0.y, c0.z, c0.w, c1.x, c1.y, c1.z, c1.w};
    a4[d] = pack8(f);   // flags (f[0] in {0.0,1.0}) survive fp16 exactly
  }

  // ---- stage-1 B-fragments: W_enc[k][e] (16 VGPRs)
  half8 we[4];
  float benc[4];
#pragma unroll
  for (int nt = 0; nt < 4; ++nt) {
    float f[8];
#pragma unroll
    for (int j = 0; j < 8; ++j)
      f[j] = W_enc[(size_t)(quad * 8 + j) * ENCD + nt * 16 + m15];
    we[nt]   = pack8(f);
    benc[nt] = b_enc[nt * 16 + m15];
  }

  // ================= stage 1 (enc MFMA) + stage 2 (masked mean-pool) =========
#pragma unroll
  for (int i = 0; i < 4; ++i) {
    // flags: lanes 0..15 hold states[b][n][0]; cumprod run via ballot+ctz
    unsigned long long bal = __ballot((l < 16) && (a4[i][0] == (_Float16)1.0f));
    int run = __builtin_ctzll(~(bal >> 1));     // consecutive valid neighbors
    float inv = 1.0f / fmaxf((float)run, 1.0f);

    const int bi = w * 4 + i;  // local batch row
#pragma unroll
    for (int nt = 0; nt < 4; ++nt) {
      f32x4 acc = {0.f, 0.f, 0.f, 0.f};
      acc = MFMA(a4[i], we[nt], acc);
      // D layout: lane holds enc[n = quad*4 + r][e = nt*16 + m15]
      float s = 0.f, e0 = 0.f;
#pragma unroll
      for (int r = 0; r < 4; ++r) {
        int n = quad * 4 + r;
        float v = fmaxf(acc[r] + benc[nt], 0.f);
        if (n == 0) e0 = v;                     // agent row
        if (n >= 1 && n <= run) s += v;         // valid neighbor
      }
      s += __shfl_xor(s, 16, 64);               // reduce across quads
      s += __shfl_xor(s, 32, 64);
      if (quad == 0) {
        f_in[bi][nt * 16 + m15]      = (_Float16)e0;        // agent_enc
        f_in[bi][64 + nt * 16 + m15] = (_Float16)(s * inv); // agg
      }
    }
  }
  __syncthreads();

  // ================= stage 3: hidden = relu(f_in @ W_f + b_f) ================
  // wave w owns N-tile w; B-frags gathered ONCE, reused for both M-tiles
  {
    const int h0 = w * 16 + m15;                // output column
    half8 wf[4];
#pragma unroll
    for (int ks = 0; ks < 4; ++ks) {
      float f[8];
#pragma unroll
      for (int j = 0; j < 8; ++j)
        f[j] = W_f[(size_t)(ks * 32 + quad * 8 + j) * HIDD + h0];
      wf[ks] = pack8(f);
    }
    const float bfv = b_f[h0];

#pragma unroll
    for (int mt = 0; mt < 2; ++mt) {
      f32x4 acc = {0.f, 0.f, 0.f, 0.f};
#pragma unroll
      for (int ks = 0; ks < 4; ++ks) {
        half8 fa = *(const half8*)&f_in[mt * 16 + m15][ks * 32 + quad * 8];
        acc = MFMA(fa, wf[ks], acc);
      }
#pragma unroll
      for (int r = 0; r < 4; ++r)               // D: row = batch, col = h0
        hidn[mt * 16 + quad * 4 + r][h0] = (_Float16)fmaxf(acc[r] + bfv, 0.f);
    }
  }
  __syncthreads();

  // ================= stage 4: logits = hidden @ W_dec + b_dec ================
  if (w < 2) {                                  // wave w -> M-tile w
    f32x4 acc = {0.f, 0.f, 0.f, 0.f};
#pragma unroll
    for (int ks = 0; ks < 4; ++ks) {
      float f[8];
#pragma unroll
      for (int j = 0; j < 8; ++j) {
        int k = ks * 32 + quad * 8 + j;
        f[j] = (m15 < OUTD) ? W_dec[(size_t)k * OUTD + m15] : 0.f;  // pad N 8->16
      }
      half8 ga = *(const half8*)&hidn[w * 16 + m15][ks * 32 + quad * 8];
      acc = MFMA(ga, pack8(f), acc);
    }
    if (m15 < OUTD) {
      const float bd = b_dec[m15];
#pragma unroll
      for (int r = 0; r < 4; ++r) {
        const int m = w * 16 + quad * 4 + r;
        out[(size_t)(b0 + m) * OUTD + m15] = acc[r] + bd;
      }
    }
  }
}

extern "C" void kernel_launch(void* const* d_in, const int* in_sizes, int n_in,
                              void* d_out, int out_size, void* d_ws, size_t ws_size,
                              hipStream_t stream) {
  (void)in_sizes; (void)n_in; (void)d_ws; (void)ws_size; (void)out_size;
  const float* obs   = (const float*)d_in[0];
  const float* W_enc = (const float*)d_in[1];
  const float* b_enc = (const float*)d_in[2];
  const float* W_f   = (const float*)d_in[3];
  const float* b_f   = (const float*)d_in[4];
  const float* W_dec = (const float*)d_in[5];
  const float* b_dec = (const float*)d_in[6];
  float* out = (float*)d_out;

  // single kernel; does not touch d_ws
  gnn_fused<<<dim3(NB / BT), dim3(THREADS), 0, stream>>>(
      obs, W_enc, b_enc, W_f, b_f, W_dec, b_dec, out);
}